// Round 15
// baseline (256.024 us; speedup 1.0000x reference)
//
#include <hip/hip_runtime.h>
#include <hip/hip_bf16.h>

// CSAA, round 15: round-8 base + sector-clean transpose feeding a k-fast P1.
//  - xpose3: x[b][c][hw] -> xt[b][hw][c] bf16, register 8x8 transpose,
//    lane-remapped so reads are 512B runs/c-row and writes are 64B FULL
//    SECTORS (4 lanes x 16B contiguous). r10/r13's xpose2 wrote 16B granules
//    (quarter-sector RMW, ~4x write amplification) - that was the poison.
//  - P1: B = xt k-fast gload16 (r13-proven): each block reads ONE contiguous
//    64KB slab -> page/TLB-friendly streaming.
//  - Everything else round-8 verbatim.
//  X  : xt[b][hw][c]       <- bf16(x)   (tile 32c x 512hw, no LDS)
//  P1 : rsz[b][p][h][w]    per (b,hw128)  B=xt k-fast gload16, K=256
//  P2 : q1,k1,v1[b][o][p][w] per (b,p,my) B=rsz bf16 n-fast (NW=3, MT64)
//  P3 : T1[b][p][o][w]     per (b,o)      flash attn
//  P4 : q2,k2,v2           per (b,c,my)   B=T1 k-fast gload16 (NW=3, MT64)
//  P5 : T2[b][h][o2][c]    per (b,o2)     flash attn, transposed epilogue
//  P6 : out[b][co][h][o2]  per (b,h,my4)  B=T2 k-fast, fp32 direct (MT64)

typedef __attribute__((ext_vector_type(8))) short bf16x8;
typedef __attribute__((ext_vector_type(4))) float f32x4;

__device__ __forceinline__ short f2b(float f) {
    __hip_bfloat16 h = __float2bfloat16(f);
    short s; __builtin_memcpy(&s, &h, 2);
    return s;
}

__device__ __forceinline__ int swx(int row) { return (row ^ (row >> 3)) & 7; }
__device__ __forceinline__ int swzb(int row, int blk) {
    return (row << 7) + ((blk ^ swx(row)) << 3);
}

__device__ __forceinline__ void gload16(const void* g, void* l) {
    __builtin_amdgcn_global_load_lds(
        (const __attribute__((address_space(1))) void*)g,
        (__attribute__((address_space(3))) void*)l, 16, 0, 0);
}

// wave computes 32 rows x 128 cols: acc[2][8]; A rows are wave-local [wr,wr+32).
__device__ __forceinline__ void mfma32x128(const short* __restrict__ SA,
                                           const short* __restrict__ SB,
                                           f32x4 (&acc)[2][8], int lane, int wr) {
    #pragma unroll
    for (int kk = 0; kk < 4; kk++) {
        const int kb = kk * 4 + (lane >> 4);
        bf16x8 a[2], b[8];
        #pragma unroll
        for (int mi = 0; mi < 2; mi++)
            a[mi] = *(const bf16x8*)&SA[swzb(wr + mi * 16 + (lane & 15), kb)];
        #pragma unroll
        for (int ni = 0; ni < 8; ni++)
            b[ni] = *(const bf16x8*)&SB[swzb(ni * 16 + (lane & 15), kb)];
        #pragma unroll
        for (int mi = 0; mi < 2; mi++)
            #pragma unroll
            for (int ni = 0; ni < 8; ni++)
                acc[mi][ni] = __builtin_amdgcn_mfma_f32_16x16x32_bf16(
                    a[mi], b[ni], acc[mi][ni], 0, 0, 0);
    }
}

// wave computes 16 rows x 128 cols: acc[8]; A rows wave-local [wr16, wr16+16).
__device__ __forceinline__ void mfma16x128(const short* __restrict__ SA,
                                           const short* __restrict__ SB,
                                           f32x4 (&acc)[8], int lane, int wr16) {
    #pragma unroll
    for (int kk = 0; kk < 4; kk++) {
        const int kb = kk * 4 + (lane >> 4);
        bf16x8 a = *(const bf16x8*)&SA[swzb(wr16 + (lane & 15), kb)];
        bf16x8 b[8];
        #pragma unroll
        for (int ni = 0; ni < 8; ni++)
            b[ni] = *(const bf16x8*)&SB[swzb(ni * 16 + (lane & 15), kb)];
        #pragma unroll
        for (int ni = 0; ni < 8; ni++)
            acc[ni] = __builtin_amdgcn_mfma_f32_16x16x32_bf16(
                a, b[ni], acc[ni], 0, 0, 0);
    }
}

__device__ __forceinline__ void stage_nf_bf16(const short* __restrict__ Bb,
                                              long long b_r, int k0,
                                              short* __restrict__ Bs, int t) {
    const int n8 = t & 15, kb = t >> 4;
    bf16x8 rk[8];
    #pragma unroll
    for (int i = 0; i < 8; i++)
        rk[i] = *(const bf16x8*)(Bb + (long long)(k0 + kb * 8 + i) * b_r + n8 * 8);
    #pragma unroll
    for (int j = 0; j < 8; j++) {
        bf16x8 col;
        #pragma unroll
        for (int i = 0; i < 8; i++) col[i] = rk[i][j];
        *(bf16x8*)&Bs[swzb(n8 * 8 + j, kb)] = col;
    }
}

// ---------------- xpose3: x[b][c][hw] -> xt[b][hw][c] bf16 -----------------
// Tile 32c x 512hw. Lane map: g=t&3 (c-octet), h=t>>2 (hw-octet).
// Read (per wave instr): 4 c-rows x 512B contiguous runs.
// Write (per wave instr): 16 hw-rows x 64B contiguous (FULL sector, no RMW).
__global__ __launch_bounds__(256)
void xpose3(const float* __restrict__ x, short* __restrict__ xt) {
    const int t = threadIdx.x;
    const int g = t & 3;
    const int h = t >> 2;
    const int hw0 = blockIdx.x * 512;
    const int c0  = blockIdx.y * 32;
    const long long boff = (long long)blockIdx.z * 4194304LL;
    const float* xb = x + boff + (long long)(c0 + g * 8) * 16384 + hw0 + h * 8;
    short* xtb = xt + boff + (long long)(hw0 + h * 8) * 256 + c0 + g * 8;

    bf16x8 rk[8];
    #pragma unroll
    for (int i = 0; i < 8; i++) {
        const float* s = xb + (long long)i * 16384;
        float4 v0 = *(const float4*)s, v1 = *(const float4*)(s + 4);
        rk[i][0] = f2b(v0.x); rk[i][1] = f2b(v0.y);
        rk[i][2] = f2b(v0.z); rk[i][3] = f2b(v0.w);
        rk[i][4] = f2b(v1.x); rk[i][5] = f2b(v1.y);
        rk[i][6] = f2b(v1.z); rk[i][7] = f2b(v1.w);
    }
    #pragma unroll
    for (int j = 0; j < 8; j++) {
        bf16x8 col;
        #pragma unroll
        for (int i = 0; i < 8; i++) col[i] = rk[i][j];
        *(bf16x8*)(xtb + (long long)j * 256) = col;
    }
}

// ---------------- wprep: fp32 weights -> bf16 page-swizzled images ---------
__global__ __launch_bounds__(256)
void wprep(const float* __restrict__ Wr, const float* __restrict__ Wqw,
           const float* __restrict__ Wkw, const float* __restrict__ Wvw,
           const float* __restrict__ Wqh, const float* __restrict__ Wkh,
           const float* __restrict__ Wvh, const float* __restrict__ Wo,
           short* __restrict__ dst) {
    const int id = blockIdx.y;
    const float* W; int M, K, off;
    switch (id) {
        case 0: W = Wr;  M = 128; K = 256; off = 0;      break;
        case 1: W = Wqw; M = 128; K = 128; off = 32768;  break;
        case 2: W = Wkw; M = 128; K = 128; off = 49152;  break;
        case 3: W = Wvw; M = 128; K = 128; off = 65536;  break;
        case 4: W = Wqh; M = 128; K = 128; off = 81920;  break;
        case 5: W = Wkh; M = 128; K = 128; off = 98304;  break;
        case 6: W = Wvh; M = 128; K = 128; off = 114688; break;
        default: W = Wo; M = 256; K = 128; off = 131072; break;
    }
    int g = blockIdx.x * 256 + threadIdx.x;
    if (g >= (M * K) >> 3) return;
    int gpr = K >> 3;
    int row = g / gpr;
    int blk = g - row * gpr;
    int ks = blk >> 4, bi = blk & 15;
    int my = row >> 7, r = row & 127;
    int nks = K >> 7;
    const float* s = W + (long long)row * K + blk * 8;
    float4 v0 = *(const float4*)s, v1 = *(const float4*)(s + 4);
    bf16x8 ov;
    ov[0] = f2b(v0.x); ov[1] = f2b(v0.y); ov[2] = f2b(v0.z); ov[3] = f2b(v0.w);
    ov[4] = f2b(v1.x); ov[5] = f2b(v1.y); ov[6] = f2b(v1.z); ov[7] = f2b(v1.w);
    *(bf16x8*)(dst + off + (my * nks + ks) * 16384 + swzb(r, bi)) = ov;
}

// ---------------- P1: 128-tile, K=256, B = xt k-fast (contiguous slab) -----
__global__ __launch_bounds__(256)
void gemm_p1(const short* __restrict__ A0, const float* __restrict__ bias0,
             const short* __restrict__ Bsrc,
             long long b_z, long long b_x, long long b_r,
             short* __restrict__ C0,
             long long c_z, long long c_x, long long c_m) {
    __shared__ short As[16384];
    __shared__ short Bs[16384];
    const int t = threadIdx.x;
    const int lane = t & 63;
    const int wid = t >> 6;
    const int wr = wid * 32;
    const int bx = blockIdx.x, bz = blockIdx.z;

    f32x4 acc[2][8];
    #pragma unroll
    for (int mi = 0; mi < 2; mi++)
        #pragma unroll
        for (int ni = 0; ni < 8; ni++) acc[mi][ni] = (f32x4){0.f, 0.f, 0.f, 0.f};

    const short* Bb = Bsrc + bz * b_z + bx * b_x;
    #pragma unroll
    for (int ks = 0; ks < 2; ks++) {
        if (ks) __syncthreads();                       // all done reading Bs
        #pragma unroll
        for (int i = 0; i < 8; i++) {
            int q = wid * 8 + i;
            int row = q * 4 + (lane >> 4);
            gload16(Bb + (long long)row * b_r + ks * 128
                       + (((lane & 15) ^ swx(row)) << 3), &Bs[q * 512]);
        }
        const short* Ai = A0 + ks * 16384;
        #pragma unroll
        for (int i = 0; i < 8; i++) {
            int q = wid * 8 + i;                       // wave-local rows
            gload16(Ai + q * 512 + lane * 8, &As[q * 512]);
        }
        __syncthreads();
        mfma32x128(As, Bs, acc, lane, wr);
    }

    // wave-local epilogue: bounce into own As rows, store own rows
    #pragma unroll
    for (int mi = 0; mi < 2; mi++)
        #pragma unroll
        for (int r = 0; r < 4; r++) {
            int row = wr + mi * 16 + (lane >> 4) * 4 + r;
            float bb = bias0[row];
            #pragma unroll
            for (int ni = 0; ni < 8; ni++) {
                int col = ni * 16 + (lane & 15);
                As[swzb(row, col >> 3) + (col & 7)] = f2b(acc[mi][ni][r] + bb);
            }
        }
    short* Cg = C0 + bz * c_z + bx * c_x;
    #pragma unroll
    for (int i = 0; i < 8; i++) {
        int idx = lane + i * 64;
        int row = wr + (idx >> 4), ch = idx & 15;
        *(bf16x8*)(Cg + (long long)row * c_m + ch * 8) =
            *(const bf16x8*)&As[swzb(row, ch)];
    }
}

// ---------------- MT64 weight-GEMM: wave-owns-16-rows (round-8) ------------
template<int NW, int BMODE, bool F32OUT>
__global__ __launch_bounds__(256, 3)
void gemmw64(const short* __restrict__ A0, const short* __restrict__ A1,
             const short* __restrict__ A2,
             const float* __restrict__ bias0, const float* __restrict__ bias1,
             const float* __restrict__ bias2,
             const void* __restrict__ Bsrc, long long b_z, long long b_x,
             long long b_r,
             short* __restrict__ C0, short* __restrict__ C1,
             short* __restrict__ C2, float* __restrict__ Cf,
             long long c_z, long long c_x, long long c_m) {
    __shared__ short As[8192];     // 64 rows x 128 k
    __shared__ short Bs[16384];    // 128 n x 128 k
    const int t = threadIdx.x;
    const int lane = t & 63;
    const int wid = t >> 6;
    const int wr16 = wid * 16;
    const int bx = blockIdx.x, my = blockIdx.y, bz = blockIdx.z;
    const int mbase = my * 64;

    // stage B (cooperative)
    if (BMODE == 0) {
        const short* Bb = (const short*)Bsrc + bz * b_z + bx * b_x;
        #pragma unroll
        for (int i = 0; i < 8; i++) {
            int q = wid * 8 + i;
            int row = q * 4 + (lane >> 4);
            gload16(Bb + (long long)row * b_r + (((lane & 15) ^ swx(row)) << 3),
                    &Bs[q * 512]);
        }
    } else {
        stage_nf_bf16((const short*)Bsrc + bz * b_z + bx * b_x, b_r, 0, Bs, t);
    }
    // stage A g=0 (wave-local rows [wr16, wr16+16))
    {
        const short* Ai = A0 + my * 8192;
        #pragma unroll
        for (int i = 0; i < 4; i++) {
            int q = wid * 4 + i;
            gload16(Ai + q * 512 + lane * 8, &As[q * 512]);
        }
    }
    __syncthreads();

    #pragma unroll
    for (int g = 0; g < NW; g++) {
        const float* bias = (g == 0) ? bias0 : (g == 1) ? bias1 : bias2;
        f32x4 acc[8];
        #pragma unroll
        for (int ni = 0; ni < 8; ni++) acc[ni] = (f32x4){0.f, 0.f, 0.f, 0.f};
        mfma16x128(As, Bs, acc, lane, wr16);

        if (F32OUT) {
            float* Cb = Cf + bz * c_z + bx * c_x;
            #pragma unroll
            for (int r = 0; r < 4; r++) {
                int row = mbase + wr16 + (lane >> 4) * 4 + r;
                float bb = bias[row];
                float* cp = Cb + (long long)row * c_m + (lane & 15);
                #pragma unroll
                for (int ni = 0; ni < 8; ni++)
                    cp[ni * 16] = acc[ni][r] + bb;
            }
        } else {
            // wave-local bounce into own As rows + store own rows
            #pragma unroll
            for (int r = 0; r < 4; r++) {
                int row = wr16 + (lane >> 4) * 4 + r;
                float bb = bias[mbase + row];
                #pragma unroll
                for (int ni = 0; ni < 8; ni++) {
                    int col = ni * 16 + (lane & 15);
                    As[swzb(row, col >> 3) + (col & 7)] = f2b(acc[ni][r] + bb);
                }
            }
            short* Cg = ((g == 0) ? C0 : (g == 1) ? C1 : C2)
                      + bz * c_z + bx * c_x;
            #pragma unroll
            for (int i = 0; i < 4; i++) {
                int idx = lane + i * 64;
                int row = wr16 + (idx >> 4), ch = idx & 15;
                *(bf16x8*)(Cg + (long long)(mbase + row) * c_m + ch * 8) =
                    *(const bf16x8*)&As[swzb(row, ch)];
            }
        }
        if (g + 1 < NW) {
            // restage A for g+1 (wave-local)
            const short* Ai = ((g == 0) ? A1 : A2) + my * 8192;
            #pragma unroll
            for (int i = 0; i < 4; i++) {
                int q = wid * 4 + i;
                gload16(Ai + q * 512 + lane * 8, &As[q * 512]);
            }
            __syncthreads();   // drains vmcnt before next mfma
        }
    }
}

// ---------------- fused attention per (b,o): wave-owns-32-rows (round-8) ---
template<bool TEPI>
__global__ __launch_bounds__(256)
void attnk(const short* __restrict__ Q, const short* __restrict__ Kp,
           const short* __restrict__ V, short* __restrict__ O) {
    __shared__ short SA[16384];
    __shared__ short SB[16384];
    const int t = threadIdx.x;
    const int lane = t & 63;
    const int wid = t >> 6;
    const int wr = wid * 32;
    const long long poff = (long long)blockIdx.z * 2097152LL
                         + (long long)blockIdx.x * 16384LL;
    const short* Qb = Q + poff;
    const short* Kb = Kp + poff;
    const short* Vb = V + poff;
    short* Ob = O + (long long)blockIdx.z * 2097152LL + (long long)blockIdx.x * 128LL;

    // stage Q (wave-local rows) + K (cooperative)
    #pragma unroll
    for (int i = 0; i < 8; i++) {
        int q = wid * 8 + i;
        int row = q * 4 + (lane >> 4);
        int sw = (((lane & 15) ^ swx(row)) << 3);
        gload16(Qb + row * 128 + sw, &SA[q * 512]);
        gload16(Kb + row * 128 + sw, &SB[q * 512]);
    }
    // V register loads (cooperative; consumed after bar2)
    const int n8 = t & 15, kb = t >> 4;
    bf16x8 vk[8];
    #pragma unroll
    for (int i = 0; i < 8; i++)
        vk[i] = *(const bf16x8*)(Vb + (kb * 8 + i) * 128 + n8 * 8);
    __syncthreads();   // bar1: Q,K staged

    f32x4 acc[2][8];
    #pragma unroll
    for (int mi = 0; mi < 2; mi++)
        #pragma unroll
        for (int ni = 0; ni < 8; ni++) acc[mi][ni] = (f32x4){0.f, 0.f, 0.f, 0.f};
    mfma32x128(SA, SB, acc, lane, wr);

    // register softmax per row; write unscaled P into own SA rows
    float rs[2][4];
    #pragma unroll
    for (int mi = 0; mi < 2; mi++)
        #pragma unroll
        for (int r = 0; r < 4; r++) {
            float mx = acc[mi][0][r];
            #pragma unroll
            for (int ni = 1; ni < 8; ni++) mx = fmaxf(mx, acc[mi][ni][r]);
            #pragma unroll
            for (int d = 1; d < 16; d <<= 1) mx = fmaxf(mx, __shfl_xor(mx, d, 64));
            float s = 0.f;
            float p[8];
            #pragma unroll
            for (int ni = 0; ni < 8; ni++) {
                p[ni] = __expf(acc[mi][ni][r] - mx);
                s += p[ni];
            }
            #pragma unroll
            for (int d = 1; d < 16; d <<= 1) s += __shfl_xor(s, d, 64);
            rs[mi][r] = 1.f / s;
            int row = wr + mi * 16 + (lane >> 4) * 4 + r;
            #pragma unroll
            for (int ni = 0; ni < 8; ni++) {
                int col = ni * 16 + (lane & 15);
                SA[swzb(row, col >> 3) + (col & 7)] = f2b(p[ni]);
            }
        }
    __syncthreads();   // bar2: all waves done reading K (SB)

    // V transpose into SB (cooperative)
    #pragma unroll
    for (int j = 0; j < 8; j++) {
        bf16x8 col;
        #pragma unroll
        for (int i = 0; i < 8; i++) col[i] = vk[i][j];
        *(bf16x8*)&SB[swzb(n8 * 8 + j, kb)] = col;
    }
    __syncthreads();   // bar3: V staged (P is wave-local)

    f32x4 acc2[2][8];
    #pragma unroll
    for (int mi = 0; mi < 2; mi++)
        #pragma unroll
        for (int ni = 0; ni < 8; ni++) acc2[mi][ni] = (f32x4){0.f, 0.f, 0.f, 0.f};
    mfma32x128(SA, SB, acc2, lane, wr);

    if (!TEPI) {
        // wave-local: bounce scaled output into own SA rows (P dead), store
        #pragma unroll
        for (int mi = 0; mi < 2; mi++)
            #pragma unroll
            for (int r = 0; r < 4; r++) {
                int row = wr + mi * 16 + (lane >> 4) * 4 + r;
                float rinv = rs[mi][r];
                #pragma unroll
                for (int ni = 0; ni < 8; ni++) {
                    int col = ni * 16 + (lane & 15);
                    SA[swzb(row, col >> 3) + (col & 7)] = f2b(acc2[mi][ni][r] * rinv);
                }
            }
        #pragma unroll
        for (int i = 0; i < 8; i++) {
            int idx = lane + i * 64;
            int row = wr + (idx >> 4), ch = idx & 15;
            *(bf16x8*)(Ob + (long long)row * 16384 + ch * 8) =
                *(const bf16x8*)&SA[swzb(row, ch)];
        }
    } else {
        __syncthreads();   // bar4: all done reading SB (V)
        #pragma unroll
        for (int mi = 0; mi < 2; mi++)
            #pragma unroll
            for (int r = 0; r < 4; r++) {
                int row = wr + mi * 16 + (lane >> 4) * 4 + r;
                float rinv = rs[mi][r];
                #pragma unroll
                for (int ni = 0; ni < 8; ni++) {
                    int col = ni * 16 + (lane & 15);
                    SB[swzb(col, row >> 3) + (row & 7)] = f2b(acc2[mi][ni][r] * rinv);
                }
            }
        __syncthreads();   // bar5
        #pragma unroll
        for (int i = 0; i < 8; i++) {
            int idx = t + i * 256;
            int row = idx >> 4, ch = idx & 15;
            *(bf16x8*)(Ob + (long long)row * 16384 + ch * 8) =
                *(const bf16x8*)&SB[swzb(row, ch)];
        }
    }
}

extern "C" void kernel_launch(void* const* d_in, const int* in_sizes, int n_in,
                              void* d_out, int out_size, void* d_ws, size_t ws_size,
                              hipStream_t stream) {
    const float* x   = (const float*)d_in[0];
    const float* Wr  = (const float*)d_in[1];
    const float* br  = (const float*)d_in[2];
    const float* Wqw = (const float*)d_in[3];
    const float* bqw = (const float*)d_in[4];
    const float* Wkw = (const float*)d_in[5];
    const float* bkw = (const float*)d_in[6];
    const float* Wvw = (const float*)d_in[7];
    const float* bvw = (const float*)d_in[8];
    const float* Wqh = (const float*)d_in[9];
    const float* bqh = (const float*)d_in[10];
    const float* Wkh = (const float*)d_in[11];
    const float* bkh = (const float*)d_in[12];
    const float* Wvh = (const float*)d_in[13];
    const float* bvh = (const float*)d_in[14];
    const float* Wo  = (const float*)d_in[15];
    const float* bo  = (const float*)d_in[16];
    float* out = (float*)d_out;
    (void)in_sizes; (void)n_in; (void)out_size; (void)ws_size;

    // bf16 workspace, U = 8*128^3 elems. s0..s3 = 0..4U; xt = 4U..6U; wb = 6U.
    // s0: rsz -> T1 -> T2 ; s1: q1 -> q2 ; s2: k1 -> k2 ; s3: v1 -> v2.
    const long long U = 16777216LL;
    short* wsp = (short*)d_ws;
    short* s0 = wsp;
    short* s1 = wsp + U;
    short* s2 = wsp + 2 * U;
    short* s3 = wsp + 3 * U;
    short* xt = wsp + 4 * U;
    short* wb = wsp + 6 * U;
    short* wWr  = wb;
    short* wWqw = wb + 32768;
    short* wWkw = wb + 49152;
    short* wWvw = wb + 65536;
    short* wWqh = wb + 81920;
    short* wWkh = wb + 98304;
    short* wWvh = wb + 114688;
    short* wWo  = wb + 131072;

    dim3 blk(256);

    wprep<<<dim3(16, 8), blk, 0, stream>>>(Wr, Wqw, Wkw, Wvw, Wqh, Wkh, Wvh, Wo, wb);

    // X: xt[b][hw][c] <- bf16(x); 512B read runs, 64B full-sector writes
    xpose3<<<dim3(32, 8, 8), blk, 0, stream>>>(x, xt);

    // P1: rsz[b][p][h][w] <- Wr * xt, per (b,hw128); B = xt k-fast slab
    gemm_p1<<<dim3(128, 1, 8), blk, 0, stream>>>(
        wWr, br, xt, 4194304LL, 32768LL, 256LL,
        s0, 2097152LL, 128LL, 16384LL);

    // P2: q1,k1,v1[b][o][p][w], per (b,p,my); B = rsz bf16 n-fast, NW=3
    gemmw64<3, 1, false><<<dim3(128, 2, 8), blk, 0, stream>>>(
        wWqw, wWkw, wWvw, bqw, bkw, bvw,
        s0, 2097152LL, 16384LL, 128LL,
        s1, s2, s3, nullptr, 2097152LL, 128LL, 16384LL);

    // P3: width attention -> T1[b][p][o][w] (into s0; rsz dead)
    attnk<false><<<dim3(128, 1, 8), blk, 0, stream>>>(s1, s2, s3, s0);

    // P4: q2,k2,v2, per (b,c,my); B = T1 k-fast, NW=3
    gemmw64<3, 0, false><<<dim3(128, 2, 8), blk, 0, stream>>>(
        wWqh, wWkh, wWvh, bqh, bkh, bvh,
        s0, 2097152LL, 16384LL, 128LL,
        s1, s2, s3, nullptr, 2097152LL, 128LL, 16384LL);

    // P5: height attention -> T2[b][h][o2][c] (into s0; T1 dead)
    attnk<true><<<dim3(128, 1, 8), blk, 0, stream>>>(s1, s2, s3, s0);

    // P6: out[b][co][h][o2] fp32, per (b,h,my4); B = T2 k-fast
    gemmw64<1, 0, true><<<dim3(128, 4, 8), blk, 0, stream>>>(
        wWo, nullptr, nullptr, bo, nullptr, nullptr,
        s0, 2097152LL, 16384LL, 128LL,
        nullptr, nullptr, nullptr, out, 4194304LL, 128LL, 16384LL);
}

// Round 16
// 216.889 us; speedup vs baseline: 1.1804x; 1.1804x over previous
//
#include <hip/hip_runtime.h>
#include <hip/hip_bf16.h>

// CSAA, round 16: round-8 VERBATIM + ONE change: stage_nf_f32 restructured
// for memory-level parallelism. r9's profile showed gemm_p1 VGPR_Count=64 --
// the load->f2b dependency chain let only ~2-3 of 16 loads stay in flight
// (Little's law: 3 x 32B x 512 thr/CU / 375ns ~= 1.5 TB/s = measured).
// Fix: phase-split load-all (float4 v[8][2]) / convert / write. ~+64 VGPR,
// no occupancy change (LDS-capped at 2 blocks/CU).
//  P1 : rsz[b][p][h][w]    per (b,h)      B=x fp32 n-fast (MLP), K=256
//  P2 : q1,k1,v1[b][o][p][w] per (b,p,my) B=rsz bf16 n-fast (NW=3, MT64)
//  P3 : T1[b][p][o][w]     per (b,o)      flash attn
//  P4 : q2,k2,v2           per (b,c,my)   B=T1 k-fast gload16 (NW=3, MT64)
//  P5 : T2[b][h][o2][c]    per (b,o2)     flash attn, transposed epilogue
//  P6 : out[b][co][h][o2]  per (b,h,my4)  B=T2 k-fast, fp32 direct (MT64)

typedef __attribute__((ext_vector_type(8))) short bf16x8;
typedef __attribute__((ext_vector_type(4))) float f32x4;

__device__ __forceinline__ short f2b(float f) {
    __hip_bfloat16 h = __float2bfloat16(f);
    short s; __builtin_memcpy(&s, &h, 2);
    return s;
}

__device__ __forceinline__ int swx(int row) { return (row ^ (row >> 3)) & 7; }
__device__ __forceinline__ int swzb(int row, int blk) {
    return (row << 7) + ((blk ^ swx(row)) << 3);
}

__device__ __forceinline__ void gload16(const void* g, void* l) {
    __builtin_amdgcn_global_load_lds(
        (const __attribute__((address_space(1))) void*)g,
        (__attribute__((address_space(3))) void*)l, 16, 0, 0);
}

// wave computes 32 rows x 128 cols: acc[2][8]; A rows are wave-local [wr,wr+32).
__device__ __forceinline__ void mfma32x128(const short* __restrict__ SA,
                                           const short* __restrict__ SB,
                                           f32x4 (&acc)[2][8], int lane, int wr) {
    #pragma unroll
    for (int kk = 0; kk < 4; kk++) {
        const int kb = kk * 4 + (lane >> 4);
        bf16x8 a[2], b[8];
        #pragma unroll
        for (int mi = 0; mi < 2; mi++)
            a[mi] = *(const bf16x8*)&SA[swzb(wr + mi * 16 + (lane & 15), kb)];
        #pragma unroll
        for (int ni = 0; ni < 8; ni++)
            b[ni] = *(const bf16x8*)&SB[swzb(ni * 16 + (lane & 15), kb)];
        #pragma unroll
        for (int mi = 0; mi < 2; mi++)
            #pragma unroll
            for (int ni = 0; ni < 8; ni++)
                acc[mi][ni] = __builtin_amdgcn_mfma_f32_16x16x32_bf16(
                    a[mi], b[ni], acc[mi][ni], 0, 0, 0);
    }
}

// wave computes 16 rows x 128 cols: acc[8]; A rows wave-local [wr16, wr16+16).
__device__ __forceinline__ void mfma16x128(const short* __restrict__ SA,
                                           const short* __restrict__ SB,
                                           f32x4 (&acc)[8], int lane, int wr16) {
    #pragma unroll
    for (int kk = 0; kk < 4; kk++) {
        const int kb = kk * 4 + (lane >> 4);
        bf16x8 a = *(const bf16x8*)&SA[swzb(wr16 + (lane & 15), kb)];
        bf16x8 b[8];
        #pragma unroll
        for (int ni = 0; ni < 8; ni++)
            b[ni] = *(const bf16x8*)&SB[swzb(ni * 16 + (lane & 15), kb)];
        #pragma unroll
        for (int ni = 0; ni < 8; ni++)
            acc[ni] = __builtin_amdgcn_mfma_f32_16x16x32_bf16(
                a, b[ni], acc[ni], 0, 0, 0);
    }
}

__device__ __forceinline__ void stage_nf_bf16(const short* __restrict__ Bb,
                                              long long b_r, int k0,
                                              short* __restrict__ Bs, int t) {
    const int n8 = t & 15, kb = t >> 4;
    bf16x8 rk[8];
    #pragma unroll
    for (int i = 0; i < 8; i++)
        rk[i] = *(const bf16x8*)(Bb + (long long)(k0 + kb * 8 + i) * b_r + n8 * 8);
    #pragma unroll
    for (int j = 0; j < 8; j++) {
        bf16x8 col;
        #pragma unroll
        for (int i = 0; i < 8; i++) col[i] = rk[i][j];
        *(bf16x8*)&Bs[swzb(n8 * 8 + j, kb)] = col;
    }
}

// MLP-restructured f32 n-fast staging: phase 1 issues ALL 16 loads into a
// register block (no dependent ops between loads -> one clause, 256B/thread
// in flight); phase 2 converts; phase 3 transposes+writes.
__device__ __forceinline__ void stage_nf_f32(const float* __restrict__ Bb,
                                             long long b_r, int k0,
                                             short* __restrict__ Bs, int t) {
    const int n8 = t & 15, kb = t >> 4;
    float4 v[8][2];
    #pragma unroll
    for (int i = 0; i < 8; i++) {
        const float* s = Bb + (long long)(k0 + kb * 8 + i) * b_r + n8 * 8;
        v[i][0] = *(const float4*)s;
        v[i][1] = *(const float4*)(s + 4);
    }
    bf16x8 rk[8];
    #pragma unroll
    for (int i = 0; i < 8; i++) {
        rk[i][0] = f2b(v[i][0].x); rk[i][1] = f2b(v[i][0].y);
        rk[i][2] = f2b(v[i][0].z); rk[i][3] = f2b(v[i][0].w);
        rk[i][4] = f2b(v[i][1].x); rk[i][5] = f2b(v[i][1].y);
        rk[i][6] = f2b(v[i][1].z); rk[i][7] = f2b(v[i][1].w);
    }
    #pragma unroll
    for (int j = 0; j < 8; j++) {
        bf16x8 col;
        #pragma unroll
        for (int i = 0; i < 8; i++) col[i] = rk[i][j];
        *(bf16x8*)&Bs[swzb(n8 * 8 + j, kb)] = col;
    }
}

// ---------------- wprep: fp32 weights -> bf16 page-swizzled images ---------
__global__ __launch_bounds__(256)
void wprep(const float* __restrict__ Wr, const float* __restrict__ Wqw,
           const float* __restrict__ Wkw, const float* __restrict__ Wvw,
           const float* __restrict__ Wqh, const float* __restrict__ Wkh,
           const float* __restrict__ Wvh, const float* __restrict__ Wo,
           short* __restrict__ dst) {
    const int id = blockIdx.y;
    const float* W; int M, K, off;
    switch (id) {
        case 0: W = Wr;  M = 128; K = 256; off = 0;      break;
        case 1: W = Wqw; M = 128; K = 128; off = 32768;  break;
        case 2: W = Wkw; M = 128; K = 128; off = 49152;  break;
        case 3: W = Wvw; M = 128; K = 128; off = 65536;  break;
        case 4: W = Wqh; M = 128; K = 128; off = 81920;  break;
        case 5: W = Wkh; M = 128; K = 128; off = 98304;  break;
        case 6: W = Wvh; M = 128; K = 128; off = 114688; break;
        default: W = Wo; M = 256; K = 128; off = 131072; break;
    }
    int g = blockIdx.x * 256 + threadIdx.x;
    if (g >= (M * K) >> 3) return;
    int gpr = K >> 3;
    int row = g / gpr;
    int blk = g - row * gpr;
    int ks = blk >> 4, bi = blk & 15;
    int my = row >> 7, r = row & 127;
    int nks = K >> 7;
    const float* s = W + (long long)row * K + blk * 8;
    float4 v0 = *(const float4*)s, v1 = *(const float4*)(s + 4);
    bf16x8 ov;
    ov[0] = f2b(v0.x); ov[1] = f2b(v0.y); ov[2] = f2b(v0.z); ov[3] = f2b(v0.w);
    ov[4] = f2b(v1.x); ov[5] = f2b(v1.y); ov[6] = f2b(v1.z); ov[7] = f2b(v1.w);
    *(bf16x8*)(dst + off + (my * nks + ks) * 16384 + swzb(r, bi)) = ov;
}

// ---------------- P1: 128-tile, K=256, wave-owns-32-rows (round-8) ---------
__global__ __launch_bounds__(256)
void gemm_p1(const short* __restrict__ A0, const float* __restrict__ bias0,
             const float* __restrict__ Bsrc,
             long long b_z, long long b_x, long long b_r,
             short* __restrict__ C0,
             long long c_z, long long c_x, long long c_m) {
    __shared__ short As[16384];
    __shared__ short Bs[16384];
    const int t = threadIdx.x;
    const int lane = t & 63;
    const int wid = t >> 6;
    const int wr = wid * 32;
    const int bx = blockIdx.x, bz = blockIdx.z;

    f32x4 acc[2][8];
    #pragma unroll
    for (int mi = 0; mi < 2; mi++)
        #pragma unroll
        for (int ni = 0; ni < 8; ni++) acc[mi][ni] = (f32x4){0.f, 0.f, 0.f, 0.f};

    #pragma unroll
    for (int ks = 0; ks < 2; ks++) {
        if (ks) __syncthreads();                       // all done reading Bs
        stage_nf_f32(Bsrc + bz * b_z + bx * b_x, b_r, ks * 128, Bs, t);
        const short* Ai = A0 + ks * 16384;
        #pragma unroll
        for (int i = 0; i < 8; i++) {
            int q = wid * 8 + i;                       // wave-local rows
            gload16(Ai + q * 512 + lane * 8, &As[q * 512]);
        }
        __syncthreads();
        mfma32x128(As, Bs, acc, lane, wr);
    }

    // wave-local epilogue: bounce into own As rows, store own rows
    #pragma unroll
    for (int mi = 0; mi < 2; mi++)
        #pragma unroll
        for (int r = 0; r < 4; r++) {
            int row = wr + mi * 16 + (lane >> 4) * 4 + r;
            float bb = bias0[row];
            #pragma unroll
            for (int ni = 0; ni < 8; ni++) {
                int col = ni * 16 + (lane & 15);
                As[swzb(row, col >> 3) + (col & 7)] = f2b(acc[mi][ni][r] + bb);
            }
        }
    short* Cg = C0 + bz * c_z + bx * c_x;
    #pragma unroll
    for (int i = 0; i < 8; i++) {
        int idx = lane + i * 64;
        int row = wr + (idx >> 4), ch = idx & 15;
        *(bf16x8*)(Cg + (long long)row * c_m + ch * 8) =
            *(const bf16x8*)&As[swzb(row, ch)];
    }
}

// ---------------- MT64 weight-GEMM: wave-owns-16-rows (round-8) ------------
template<int NW, int BMODE, bool F32OUT>
__global__ __launch_bounds__(256, 3)
void gemmw64(const short* __restrict__ A0, const short* __restrict__ A1,
             const short* __restrict__ A2,
             const float* __restrict__ bias0, const float* __restrict__ bias1,
             const float* __restrict__ bias2,
             const void* __restrict__ Bsrc, long long b_z, long long b_x,
             long long b_r,
             short* __restrict__ C0, short* __restrict__ C1,
             short* __restrict__ C2, float* __restrict__ Cf,
             long long c_z, long long c_x, long long c_m) {
    __shared__ short As[8192];     // 64 rows x 128 k
    __shared__ short Bs[16384];    // 128 n x 128 k
    const int t = threadIdx.x;
    const int lane = t & 63;
    const int wid = t >> 6;
    const int wr16 = wid * 16;
    const int bx = blockIdx.x, my = blockIdx.y, bz = blockIdx.z;
    const int mbase = my * 64;

    // stage B (cooperative)
    if (BMODE == 0) {
        const short* Bb = (const short*)Bsrc + bz * b_z + bx * b_x;
        #pragma unroll
        for (int i = 0; i < 8; i++) {
            int q = wid * 8 + i;
            int row = q * 4 + (lane >> 4);
            gload16(Bb + (long long)row * b_r + (((lane & 15) ^ swx(row)) << 3),
                    &Bs[q * 512]);
        }
    } else {
        stage_nf_bf16((const short*)Bsrc + bz * b_z + bx * b_x, b_r, 0, Bs, t);
    }
    // stage A g=0 (wave-local rows [wr16, wr16+16))
    {
        const short* Ai = A0 + my * 8192;
        #pragma unroll
        for (int i = 0; i < 4; i++) {
            int q = wid * 4 + i;
            gload16(Ai + q * 512 + lane * 8, &As[q * 512]);
        }
    }
    __syncthreads();

    #pragma unroll
    for (int g = 0; g < NW; g++) {
        const float* bias = (g == 0) ? bias0 : (g == 1) ? bias1 : bias2;
        f32x4 acc[8];
        #pragma unroll
        for (int ni = 0; ni < 8; ni++) acc[ni] = (f32x4){0.f, 0.f, 0.f, 0.f};
        mfma16x128(As, Bs, acc, lane, wr16);

        if (F32OUT) {
            float* Cb = Cf + bz * c_z + bx * c_x;
            #pragma unroll
            for (int r = 0; r < 4; r++) {
                int row = mbase + wr16 + (lane >> 4) * 4 + r;
                float bb = bias[row];
                float* cp = Cb + (long long)row * c_m + (lane & 15);
                #pragma unroll
                for (int ni = 0; ni < 8; ni++)
                    cp[ni * 16] = acc[ni][r] + bb;
            }
        } else {
            // wave-local bounce into own As rows + store own rows
            #pragma unroll
            for (int r = 0; r < 4; r++) {
                int row = wr16 + (lane >> 4) * 4 + r;
                float bb = bias[mbase + row];
                #pragma unroll
                for (int ni = 0; ni < 8; ni++) {
                    int col = ni * 16 + (lane & 15);
                    As[swzb(row, col >> 3) + (col & 7)] = f2b(acc[ni][r] + bb);
                }
            }
            short* Cg = ((g == 0) ? C0 : (g == 1) ? C1 : C2)
                      + bz * c_z + bx * c_x;
            #pragma unroll
            for (int i = 0; i < 4; i++) {
                int idx = lane + i * 64;
                int row = wr16 + (idx >> 4), ch = idx & 15;
                *(bf16x8*)(Cg + (long long)(mbase + row) * c_m + ch * 8) =
                    *(const bf16x8*)&As[swzb(row, ch)];
            }
        }
        if (g + 1 < NW) {
            // restage A for g+1 (wave-local)
            const short* Ai = ((g == 0) ? A1 : A2) + my * 8192;
            #pragma unroll
            for (int i = 0; i < 4; i++) {
                int q = wid * 4 + i;
                gload16(Ai + q * 512 + lane * 8, &As[q * 512]);
            }
            __syncthreads();   // drains vmcnt before next mfma
        }
    }
}

// ---------------- fused attention per (b,o): wave-owns-32-rows (round-8) ---
template<bool TEPI>
__global__ __launch_bounds__(256)
void attnk(const short* __restrict__ Q, const short* __restrict__ Kp,
           const short* __restrict__ V, short* __restrict__ O) {
    __shared__ short SA[16384];
    __shared__ short SB[16384];
    const int t = threadIdx.x;
    const int lane = t & 63;
    const int wid = t >> 6;
    const int wr = wid * 32;
    const long long poff = (long long)blockIdx.z * 2097152LL
                         + (long long)blockIdx.x * 16384LL;
    const short* Qb = Q + poff;
    const short* Kb = Kp + poff;
    const short* Vb = V + poff;
    short* Ob = O + (long long)blockIdx.z * 2097152LL + (long long)blockIdx.x * 128LL;

    // stage Q (wave-local rows) + K (cooperative)
    #pragma unroll
    for (int i = 0; i < 8; i++) {
        int q = wid * 8 + i;
        int row = q * 4 + (lane >> 4);
        int sw = (((lane & 15) ^ swx(row)) << 3);
        gload16(Qb + row * 128 + sw, &SA[q * 512]);
        gload16(Kb + row * 128 + sw, &SB[q * 512]);
    }
    // V register loads (cooperative; consumed after bar2)
    const int n8 = t & 15, kb = t >> 4;
    bf16x8 vk[8];
    #pragma unroll
    for (int i = 0; i < 8; i++)
        vk[i] = *(const bf16x8*)(Vb + (kb * 8 + i) * 128 + n8 * 8);
    __syncthreads();   // bar1: Q,K staged

    f32x4 acc[2][8];
    #pragma unroll
    for (int mi = 0; mi < 2; mi++)
        #pragma unroll
        for (int ni = 0; ni < 8; ni++) acc[mi][ni] = (f32x4){0.f, 0.f, 0.f, 0.f};
    mfma32x128(SA, SB, acc, lane, wr);

    // register softmax per row; write unscaled P into own SA rows
    float rs[2][4];
    #pragma unroll
    for (int mi = 0; mi < 2; mi++)
        #pragma unroll
        for (int r = 0; r < 4; r++) {
            float mx = acc[mi][0][r];
            #pragma unroll
            for (int ni = 1; ni < 8; ni++) mx = fmaxf(mx, acc[mi][ni][r]);
            #pragma unroll
            for (int d = 1; d < 16; d <<= 1) mx = fmaxf(mx, __shfl_xor(mx, d, 64));
            float s = 0.f;
            float p[8];
            #pragma unroll
            for (int ni = 0; ni < 8; ni++) {
                p[ni] = __expf(acc[mi][ni][r] - mx);
                s += p[ni];
            }
            #pragma unroll
            for (int d = 1; d < 16; d <<= 1) s += __shfl_xor(s, d, 64);
            rs[mi][r] = 1.f / s;
            int row = wr + mi * 16 + (lane >> 4) * 4 + r;
            #pragma unroll
            for (int ni = 0; ni < 8; ni++) {
                int col = ni * 16 + (lane & 15);
                SA[swzb(row, col >> 3) + (col & 7)] = f2b(p[ni]);
            }
        }
    __syncthreads();   // bar2: all waves done reading K (SB)

    // V transpose into SB (cooperative)
    #pragma unroll
    for (int j = 0; j < 8; j++) {
        bf16x8 col;
        #pragma unroll
        for (int i = 0; i < 8; i++) col[i] = vk[i][j];
        *(bf16x8*)&SB[swzb(n8 * 8 + j, kb)] = col;
    }
    __syncthreads();   // bar3: V staged (P is wave-local)

    f32x4 acc2[2][8];
    #pragma unroll
    for (int mi = 0; mi < 2; mi++)
        #pragma unroll
        for (int ni = 0; ni < 8; ni++) acc2[mi][ni] = (f32x4){0.f, 0.f, 0.f, 0.f};
    mfma32x128(SA, SB, acc2, lane, wr);

    if (!TEPI) {
        // wave-local: bounce scaled output into own SA rows (P dead), store
        #pragma unroll
        for (int mi = 0; mi < 2; mi++)
            #pragma unroll
            for (int r = 0; r < 4; r++) {
                int row = wr + mi * 16 + (lane >> 4) * 4 + r;
                float rinv = rs[mi][r];
                #pragma unroll
                for (int ni = 0; ni < 8; ni++) {
                    int col = ni * 16 + (lane & 15);
                    SA[swzb(row, col >> 3) + (col & 7)] = f2b(acc2[mi][ni][r] * rinv);
                }
            }
        #pragma unroll
        for (int i = 0; i < 8; i++) {
            int idx = lane + i * 64;
            int row = wr + (idx >> 4), ch = idx & 15;
            *(bf16x8*)(Ob + (long long)row * 16384 + ch * 8) =
                *(const bf16x8*)&SA[swzb(row, ch)];
        }
    } else {
        __syncthreads();   // bar4: all done reading SB (V)
        #pragma unroll
        for (int mi = 0; mi < 2; mi++)
            #pragma unroll
            for (int r = 0; r < 4; r++) {
                int row = wr + mi * 16 + (lane >> 4) * 4 + r;
                float rinv = rs[mi][r];
                #pragma unroll
                for (int ni = 0; ni < 8; ni++) {
                    int col = ni * 16 + (lane & 15);
                    SB[swzb(col, row >> 3) + (row & 7)] = f2b(acc2[mi][ni][r] * rinv);
                }
            }
        __syncthreads();   // bar5
        #pragma unroll
        for (int i = 0; i < 8; i++) {
            int idx = t + i * 256;
            int row = idx >> 4, ch = idx & 15;
            *(bf16x8*)(Ob + (long long)row * 16384 + ch * 8) =
                *(const bf16x8*)&SB[swzb(row, ch)];
        }
    }
}

extern "C" void kernel_launch(void* const* d_in, const int* in_sizes, int n_in,
                              void* d_out, int out_size, void* d_ws, size_t ws_size,
                              hipStream_t stream) {
    const float* x   = (const float*)d_in[0];
    const float* Wr  = (const float*)d_in[1];
    const float* br  = (const float*)d_in[2];
    const float* Wqw = (const float*)d_in[3];
    const float* bqw = (const float*)d_in[4];
    const float* Wkw = (const float*)d_in[5];
    const float* bkw = (const float*)d_in[6];
    const float* Wvw = (const float*)d_in[7];
    const float* bvw = (const float*)d_in[8];
    const float* Wqh = (const float*)d_in[9];
    const float* bqh = (const float*)d_in[10];
    const float* Wkh = (const float*)d_in[11];
    const float* bkh = (const float*)d_in[12];
    const float* Wvh = (const float*)d_in[13];
    const float* bvh = (const float*)d_in[14];
    const float* Wo  = (const float*)d_in[15];
    const float* bo  = (const float*)d_in[16];
    float* out = (float*)d_out;
    (void)in_sizes; (void)n_in; (void)out_size; (void)ws_size;

    // bf16 workspace, U = 8*128^3 elems (33.5MB). 4U tensors + weight images.
    // s0: rsz -> T1 -> T2 ; s1: q1 -> q2 ; s2: k1 -> k2 ; s3: v1 -> v2.
    const long long U = 16777216LL;
    short* wsp = (short*)d_ws;
    short* s0 = wsp;
    short* s1 = wsp + U;
    short* s2 = wsp + 2 * U;
    short* s3 = wsp + 3 * U;
    short* wb = wsp + 4 * U;
    short* wWr  = wb;
    short* wWqw = wb + 32768;
    short* wWkw = wb + 49152;
    short* wWvw = wb + 65536;
    short* wWqh = wb + 81920;
    short* wWkh = wb + 98304;
    short* wWvh = wb + 114688;
    short* wWo  = wb + 131072;

    dim3 blk(256);

    wprep<<<dim3(16, 8), blk, 0, stream>>>(Wr, Wqw, Wkw, Wvw, Wqh, Wkh, Wvh, Wo, wb);

    // P1: rsz[b][p][h][w] <- x, per (b,h-chunk); B fp32 n-fast (MLP), K=256
    gemm_p1<<<dim3(128, 1, 8), blk, 0, stream>>>(
        wWr, br, x, 4194304LL, 128LL, 16384LL,
        s0, 2097152LL, 128LL, 16384LL);

    // P2: q1,k1,v1[b][o][p][w], per (b,p,my); B = rsz bf16 n-fast, NW=3
    gemmw64<3, 1, false><<<dim3(128, 2, 8), blk, 0, stream>>>(
        wWqw, wWkw, wWvw, bqw, bkw, bvw,
        s0, 2097152LL, 16384LL, 128LL,
        s1, s2, s3, nullptr, 2097152LL, 128LL, 16384LL);

    // P3: width attention -> T1[b][p][o][w] (into s0; rsz dead)
    attnk<false><<<dim3(128, 1, 8), blk, 0, stream>>>(s1, s2, s3, s0);

    // P4: q2,k2,v2, per (b,c,my); B = T1 k-fast, NW=3
    gemmw64<3, 0, false><<<dim3(128, 2, 8), blk, 0, stream>>>(
        wWqh, wWkh, wWvh, bqh, bkh, bvh,
        s0, 2097152LL, 16384LL, 128LL,
        s1, s2, s3, nullptr, 2097152LL, 128LL, 16384LL);

    // P5: height attention -> T2[b][h][o2][c] (into s0; T1 dead)
    attnk<true><<<dim3(128, 1, 8), blk, 0, stream>>>(s1, s2, s3, s0);

    // P6: out[b][co][h][o2] fp32, per (b,h,my4); B = T2 k-fast
    gemmw64<1, 0, true><<<dim3(128, 4, 8), blk, 0, stream>>>(
        wWo, nullptr, nullptr, bo, nullptr, nullptr,
        s0, 2097152LL, 16384LL, 128LL,
        nullptr, nullptr, nullptr, out, 4194304LL, 128LL, 16384LL);
}